// Round 1
// baseline (820.397 us; speedup 1.0000x reference)
//
#include <hip/hip_runtime.h>
#include <math.h>

// Problem constants (fixed by the reference setup)
#define NEL 10
#define FD 64
#define NBES 8
#define GG 20
#define HML 16

__device__ __forceinline__ float wred(float v) {
    #pragma unroll
    for (int off = 32; off > 0; off >>= 1) v += __shfl_down(v, off, 64);
    return v;
}

__device__ __forceinline__ float silu(float h) {
    return h / (1.f + __expf(-h));
}

// Per-node setup: species, E0, formal charge, node-part of polarization
__global__ __launch_bounds__(256) void setup_nodes_k(
    const float* __restrict__ attrs, const float* __restrict__ pos,
    const float* __restrict__ ae, const float* __restrict__ fc,
    int* __restrict__ spec, float* __restrict__ q,
    float* __restrict__ out_nodeE, float* __restrict__ ge0,
    float* __restrict__ polA, int N_, int ng)
{
    __shared__ float lge[GG];
    __shared__ float lpol[GG][3];
    int tid = threadIdx.x;
    if (tid < GG) { lge[tid] = 0.f; lpol[tid][0] = 0.f; lpol[tid][1] = 0.f; lpol[tid][2] = 0.f; }
    __syncthreads();
    int n = blockIdx.x * 256 + tid;
    if (n < N_) {
        const float* row = attrs + (size_t)n * NEL;
        int sp = 0;
        #pragma unroll
        for (int i = 0; i < NEL; ++i) if (row[i] > 0.5f) sp = i;
        spec[n] = sp;
        float e0n = ae[sp];
        out_nodeE[n] = e0n;
        float fq = fc[sp];
        q[n] = fq;
        int g = n / ng;
        atomicAdd(&lge[g], e0n);
        atomicAdd(&lpol[g][0], fq * pos[(size_t)n*3 + 0]);
        atomicAdd(&lpol[g][1], fq * pos[(size_t)n*3 + 1]);
        atomicAdd(&lpol[g][2], fq * pos[(size_t)n*3 + 2]);
    }
    __syncthreads();
    if (tid < GG) {
        atomicAdd(&ge0[tid], lge[tid]);
        atomicAdd(&polA[tid*3+0], lpol[tid][0]);
        atomicAdd(&polA[tid*3+1], lpol[tid][1]);
        atomicAdd(&polA[tid*3+2], lpol[tid][2]);
    }
}

__global__ __launch_bounds__(256) void init_scal_k(
    float* __restrict__ scal, const float* __restrict__ embed_w,
    const int* __restrict__ spec, int N_)
{
    int idx = blockIdx.x * 256 + threadIdx.x;
    if (idx < N_ * FD) {
        int n = idx >> 6, f = idx & 63;
        scal[idx] = embed_w[spec[n] * FD + f];
    }
}

// Edge geometry: bessel basis with poly cutoff (layer-invariant), flux, edge-part of polarization
__global__ __launch_bounds__(256) void edge_geom_k(
    const float* __restrict__ pos, const int* __restrict__ eidx,
    const float* __restrict__ flux_w, float* __restrict__ ef,
    float* __restrict__ polA, int E_, int ng)
{
    __shared__ float lpol[GG][3];
    int tid = threadIdx.x;
    if (tid < GG) { lpol[tid][0] = 0.f; lpol[tid][1] = 0.f; lpol[tid][2] = 0.f; }
    __syncthreads();
    float fw[NBES];
    #pragma unroll
    for (int i = 0; i < NBES; ++i) fw[i] = flux_w[i] + flux_w[NBES + i];
    const float PI = 3.14159265358979323846f;
    for (int e = blockIdx.x * 256 + tid; e < E_; e += gridDim.x * 256) {
        int s = eidx[e], r = eidx[E_ + e];
        float dx = pos[(size_t)r*3+0] - pos[(size_t)s*3+0];
        float dy = pos[(size_t)r*3+1] - pos[(size_t)s*3+1];
        float dz = pos[(size_t)r*3+2] - pos[(size_t)s*3+2];
        float len = sqrtf(dx*dx + dy*dy + dz*dz + 1e-12f);
        float x = len * 0.2f;
        float u = 0.f;
        if (x < 1.f) {
            float x2 = x * x;
            float x5 = x2 * x2 * x;
            u = 1.f - 21.f * x5 + 35.f * x5 * x - 15.f * x5 * x2;
        }
        float pref = 0.6324555320336759f / len * u;   // sqrt(2/5)/r * u
        float arg = PI * len * 0.2f;
        float flux = 0.f;
        #pragma unroll
        for (int i = 0; i < NBES; ++i) {
            float rb = pref * sinf((float)(i + 1) * arg);
            ef[(size_t)e * NBES + i] = rb;
            flux += rb * fw[i];
        }
        int g = r / ng;
        atomicAdd(&lpol[g][0], flux * dx);
        atomicAdd(&lpol[g][1], flux * dy);
        atomicAdd(&lpol[g][2], flux * dz);
    }
    __syncthreads();
    if (tid < GG) {
        atomicAdd(&polA[tid*3+0], lpol[tid][0]);
        atomicAdd(&polA[tid*3+1], lpol[tid][1]);
        atomicAdd(&polA[tid*3+2], lpol[tid][2]);
    }
}

// Radial MLP + message + scatter. Wave handles 8 edges; lane = hidden unit (phase1) / feature (phase2).
__global__ __launch_bounds__(256) void edge_mlp_k(
    const float* __restrict__ ef, const int* __restrict__ eidx,
    const float* __restrict__ w1, const float* __restrict__ b1,
    const float* __restrict__ w2, const float* __restrict__ scal,
    float* __restrict__ agg0, int layer, int E_)
{
    __shared__ float hsh[4][8][FD];
    int wid = threadIdx.x >> 6, lane = threadIdx.x & 63;
    int e0 = (blockIdx.x * 4 + wid) * 8;

    // phase 1: lane = hidden unit k
    float bk = b1[layer * FD + lane];
    float w1k[NBES];
    #pragma unroll
    for (int i = 0; i < NBES; ++i) w1k[i] = w1[(layer * NBES + i) * FD + lane];
    #pragma unroll
    for (int e = 0; e < 8; ++e) {
        int ee = e0 + e;
        float h = bk;
        if (ee < E_) {
            const float* efe = ef + (size_t)ee * NBES;
            #pragma unroll
            for (int i = 0; i < NBES; ++i) h += efe[i] * w1k[i];
        }
        hsh[wid][e][lane] = silu(h);
    }
    __syncthreads();

    // phase 2: lane = output feature f
    float acc[8];
    #pragma unroll
    for (int e = 0; e < 8; ++e) acc[e] = 0.f;
    const float* w2l = w2 + (size_t)layer * FD * FD;
    for (int k = 0; k < FD; ++k) {
        float wv = w2l[k * FD + lane];
        #pragma unroll
        for (int e = 0; e < 8; ++e) acc[e] += hsh[wid][e][k] * wv;
    }
    #pragma unroll
    for (int e = 0; e < 8; ++e) {
        int ee = e0 + e;
        if (ee < E_) {
            int s = eidx[ee], r = eidx[E_ + ee];
            float A = acc[e] * scal[(size_t)s * FD + lane];
            atomicAdd(&agg0[(size_t)r * FD + lane], A);
        }
    }
}

// Node update: scalars' = agg/16 + (agg/16)^2 + scal*prod_w[spec]; readout energies; charge update.
__global__ __launch_bounds__(256) void node_update_k(
    float* __restrict__ scal, float* __restrict__ agg0,
    const int* __restrict__ spec, const float* __restrict__ prod_w,
    const float* __restrict__ readout_w, const float* __restrict__ ro2_w1,
    const float* __restrict__ ro2_b1, const float* __restrict__ ro2_w2,
    const float* __restrict__ charge_w, float* __restrict__ q,
    float* __restrict__ out_nodeE, float* __restrict__ gE,
    int layer, int last, int N_, int ng)
{
    __shared__ float vsh[4][FD];
    int wid = threadIdx.x >> 6, lane = threadIdx.x & 63;
    int n = blockIdx.x * 4 + wid;
    int sp = spec[n];
    size_t idx = (size_t)n * FD + lane;
    float a = agg0[idx] * 0.0625f;
    agg0[idx] = 0.f;                       // pre-zero for next layer
    float v = a + a * a + scal[idx] * prod_w[(layer * NEL + sp) * FD + lane];
    scal[idx] = v;

    float ne;
    if (!last) {
        ne = wred(v * readout_w[layer * FD + lane]);
    } else {
        vsh[wid][lane] = v;
        __syncthreads();
        float h = 0.f;
        if (lane < HML) {
            h = ro2_b1[lane];
            for (int f = 0; f < FD; ++f) h += vsh[wid][f] * ro2_w1[f * HML + lane];
            h = silu(h) * ro2_w2[lane];
        }
        ne = wred(h);
    }
    float qs = wred(v * charge_w[layer * FD + lane]);
    if (lane == 0) {
        out_nodeE[n] += ne;
        atomicAdd(&gE[n / ng], ne);
        q[n] += qs;
    }
}

// Direct screened Coulomb per graph. Block handles a 64-wide i-chunk of one graph.
__global__ __launch_bounds__(256) void coulomb_k(
    const float* __restrict__ q, const float* __restrict__ pos,
    float* __restrict__ eel, float* __restrict__ qtot, int ng)
{
    __shared__ float qs[1024], px[1024], py[1024], pz[1024];
    __shared__ float wsum[4];
    int g = blockIdx.x >> 4, chunk = blockIdx.x & 15;
    int tid = threadIdx.x;
    const float* qg = q + (size_t)g * ng;
    const float* pg = pos + (size_t)g * ng * 3;
    for (int i = tid; i < ng; i += 256) {
        qs[i] = qg[i];
        px[i] = pg[(size_t)i*3+0]; py[i] = pg[(size_t)i*3+1]; pz[i] = pg[(size_t)i*3+2];
    }
    __syncthreads();
    int i = chunk * 64 + (tid & 63);
    int jq = tid >> 6;                      // wave id: j residue class
    float acc = 0.f;
    if (i < ng) {
        float qi = qs[i], xi = px[i], yi = py[i], zi = pz[i];
        for (int j = jq; j < ng; j += 4) {  // all lanes in a wave share j -> LDS broadcast
            float dx = xi - px[j], dy = yi - py[j], dz = zi - pz[j];
            float r = sqrtf(dx*dx + dy*dy + dz*dz + 1e-12f);
            float kern = (j == i) ? 0.f : erff(0.5f * r) / r;
            acc += qi * qs[j] * kern;
        }
    }
    acc = wred(acc);
    if ((tid & 63) == 0) wsum[tid >> 6] = acc;
    __syncthreads();
    if (tid == 0) atomicAdd(&eel[g], 0.5f * (wsum[0] + wsum[1] + wsum[2] + wsum[3]));
    if (chunk == 0 && tid < 64) {           // one block per graph computes total charge
        float s = 0.f;
        for (int k = tid; k < ng; k += 64) s += qs[k];
        s = wred(s);
        if (tid == 0) qtot[g] = s;
    }
}

__global__ void finalize_k(const float* __restrict__ acc, float* __restrict__ out,
                           int G_, int N_)
{
    int g = threadIdx.x;
    if (g < G_) {
        float a0 = acc[0 + g], a1 = acc[20 + g], a2 = acc[40 + g], ee = acc[60 + g];
        out[g] = a0 + a1 + a2 + ee;                 // total_energy
        float* contrib = out + G_ + N_;             // contributions [G,3]
        contrib[g*3+0] = a0; contrib[g*3+1] = a1; contrib[g*3+2] = a2;
        float* pol = contrib + G_ * 3;              // pol [G,3]
        pol[g*3+0] = acc[80 + g*3+0];
        pol[g*3+1] = acc[80 + g*3+1];
        pol[g*3+2] = acc[80 + g*3+2];
        float* qt = pol + G_ * 3;                   // total_charge [G]
        qt[g] = acc[140 + g];
    }
}

extern "C" void kernel_launch(void* const* d_in, const int* in_sizes, int n_in,
                              void* d_out, int out_size, void* d_ws, size_t ws_size,
                              hipStream_t stream)
{
    const float* node_attrs      = (const float*)d_in[0];
    const float* positions       = (const float*)d_in[1];
    const int*   edge_index      = (const int*)d_in[2];
    const float* atomic_energies = (const float*)d_in[5];
    const float* embed_w         = (const float*)d_in[6];
    const float* radial_w1       = (const float*)d_in[7];
    const float* radial_b1       = (const float*)d_in[8];
    const float* radial_w2       = (const float*)d_in[9];
    const float* prod_w          = (const float*)d_in[10];
    const float* readout_w       = (const float*)d_in[11];
    const float* ro2_w1          = (const float*)d_in[12];
    const float* ro2_b1          = (const float*)d_in[13];
    const float* ro2_w2          = (const float*)d_in[14];
    const float* charge_w        = (const float*)d_in[15];
    const float* flux_w          = (const float*)d_in[16];
    const float* formal_charges  = (const float*)d_in[17];

    int N = in_sizes[0] / NEL;     // 20000
    int E = in_sizes[2] / 2;       // 320000
    const int G_ = GG;             // 20
    int ng = N / G_;               // 1000

    float* ws   = (float*)d_ws;
    float* scal = ws;                              // [N,64]
    float* agg0 = scal + (size_t)N * FD;           // [N,64]
    float* ef   = agg0 + (size_t)N * FD;           // [E,8]
    float* q    = ef + (size_t)E * NBES;           // [N]
    int*   spec = (int*)(q + N);                   // [N]
    float* acc  = (float*)(spec + N);              // [160] graph accumulators

    float* out = (float*)d_out;
    float* out_nodeE = out + G_;

    hipMemsetAsync(agg0, 0, (size_t)N * FD * sizeof(float), stream);
    hipMemsetAsync(acc, 0, 160 * sizeof(float), stream);

    setup_nodes_k<<<(N + 255) / 256, 256, 0, stream>>>(
        node_attrs, positions, atomic_energies, formal_charges,
        spec, q, out_nodeE, acc + 0, acc + 80, N, ng);
    init_scal_k<<<(N * FD + 255) / 256, 256, 0, stream>>>(scal, embed_w, spec, N);
    edge_geom_k<<<512, 256, 0, stream>>>(positions, edge_index, flux_w, ef, acc + 80, E, ng);

    for (int l = 0; l < 2; ++l) {
        edge_mlp_k<<<(E + 31) / 32, 256, 0, stream>>>(
            ef, edge_index, radial_w1, radial_b1, radial_w2, scal, agg0, l, E);
        node_update_k<<<N / 4, 256, 0, stream>>>(
            scal, agg0, spec, prod_w, readout_w, ro2_w1, ro2_b1, ro2_w2,
            charge_w, q, out_nodeE, (l == 0) ? acc + 20 : acc + 40,
            l, (l == 1) ? 1 : 0, N, ng);
    }

    coulomb_k<<<G_ * 16, 256, 0, stream>>>(q, positions, acc + 60, acc + 140, ng);
    finalize_k<<<1, 64, 0, stream>>>(acc, out, G_, N);
}

// Round 2
// 441.212 us; speedup vs baseline: 1.8594x; 1.8594x over previous
//
#include <hip/hip_runtime.h>
#include <math.h>

// Problem constants (fixed by the reference setup)
#define NEL 10
#define FD 64
#define NBES 8
#define GG 20
#define HML 16

__device__ __forceinline__ float wred(float v) {
    #pragma unroll
    for (int off = 32; off > 0; off >>= 1) v += __shfl_down(v, off, 64);
    return v;
}

__device__ __forceinline__ float silu(float h) {
    return h / (1.f + __expf(-h));
}

// Per-node setup: species, E0, formal charge. NO atomics (graph sums done in graph_sum_k).
__global__ __launch_bounds__(256) void setup_nodes_k(
    const float* __restrict__ attrs, const float* __restrict__ ae,
    const float* __restrict__ fc, int* __restrict__ spec,
    float* __restrict__ q, float* __restrict__ out_nodeE, int N_)
{
    int n = blockIdx.x * 256 + threadIdx.x;
    if (n < N_) {
        const float* row = attrs + (size_t)n * NEL;
        int sp = 0;
        #pragma unroll
        for (int i = 0; i < NEL; ++i) if (row[i] > 0.5f) sp = i;
        spec[n] = sp;
        out_nodeE[n] = ae[sp];
        q[n] = fc[sp];
    }
}

__global__ __launch_bounds__(256) void init_scal_k(
    float* __restrict__ scal, const float* __restrict__ embed_w,
    const int* __restrict__ spec, int N_)
{
    int idx = blockIdx.x * 256 + threadIdx.x;
    if (idx < N_ * FD) {
        int n = idx >> 6, f = idx & 63;
        scal[idx] = embed_w[spec[n] * FD + f];
    }
}

// Edge geometry: bessel basis with poly cutoff (layer-invariant), flux, edge-part of polarization
__global__ __launch_bounds__(256) void edge_geom_k(
    const float* __restrict__ pos, const int* __restrict__ eidx,
    const float* __restrict__ flux_w, float* __restrict__ ef,
    float* __restrict__ polA, int E_, int ng)
{
    __shared__ float lpol[GG][3];
    int tid = threadIdx.x;
    if (tid < GG) { lpol[tid][0] = 0.f; lpol[tid][1] = 0.f; lpol[tid][2] = 0.f; }
    __syncthreads();
    float fw[NBES];
    #pragma unroll
    for (int i = 0; i < NBES; ++i) fw[i] = flux_w[i] + flux_w[NBES + i];
    const float PI = 3.14159265358979323846f;
    for (int e = blockIdx.x * 256 + tid; e < E_; e += gridDim.x * 256) {
        int s = eidx[e], r = eidx[E_ + e];
        float dx = pos[(size_t)r*3+0] - pos[(size_t)s*3+0];
        float dy = pos[(size_t)r*3+1] - pos[(size_t)s*3+1];
        float dz = pos[(size_t)r*3+2] - pos[(size_t)s*3+2];
        float len = sqrtf(dx*dx + dy*dy + dz*dz + 1e-12f);
        float x = len * 0.2f;
        float u = 0.f;
        if (x < 1.f) {
            float x2 = x * x;
            float x5 = x2 * x2 * x;
            u = 1.f - 21.f * x5 + 35.f * x5 * x - 15.f * x5 * x2;
        }
        float pref = 0.6324555320336759f / len * u;   // sqrt(2/5)/r * u
        float arg = PI * len * 0.2f;
        float flux = 0.f;
        #pragma unroll
        for (int i = 0; i < NBES; ++i) {
            float rb = pref * sinf((float)(i + 1) * arg);
            ef[(size_t)e * NBES + i] = rb;
            flux += rb * fw[i];
        }
        int g = r / ng;
        atomicAdd(&lpol[g][0], flux * dx);
        atomicAdd(&lpol[g][1], flux * dy);
        atomicAdd(&lpol[g][2], flux * dz);
    }
    __syncthreads();
    if (tid < GG) {
        atomicAdd(&polA[tid*3+0], lpol[tid][0]);
        atomicAdd(&polA[tid*3+1], lpol[tid][1]);
        atomicAdd(&polA[tid*3+2], lpol[tid][2]);
    }
}

// Radial MLP + message + scatter. Wave handles 8 edges; lane = hidden unit (phase1) / feature (phase2).
__global__ __launch_bounds__(256) void edge_mlp_k(
    const float* __restrict__ ef, const int* __restrict__ eidx,
    const float* __restrict__ w1, const float* __restrict__ b1,
    const float* __restrict__ w2, const float* __restrict__ scal,
    float* __restrict__ agg0, int layer, int E_)
{
    __shared__ float hsh[4][8][FD];
    int wid = threadIdx.x >> 6, lane = threadIdx.x & 63;
    int e0 = (blockIdx.x * 4 + wid) * 8;

    // phase 1: lane = hidden unit k
    float bk = b1[layer * FD + lane];
    float w1k[NBES];
    #pragma unroll
    for (int i = 0; i < NBES; ++i) w1k[i] = w1[(layer * NBES + i) * FD + lane];
    #pragma unroll
    for (int e = 0; e < 8; ++e) {
        int ee = e0 + e;
        float h = bk;
        if (ee < E_) {
            const float* efe = ef + (size_t)ee * NBES;
            #pragma unroll
            for (int i = 0; i < NBES; ++i) h += efe[i] * w1k[i];
        }
        hsh[wid][e][lane] = silu(h);
    }
    __syncthreads();

    // phase 2: lane = output feature f
    float acc[8];
    #pragma unroll
    for (int e = 0; e < 8; ++e) acc[e] = 0.f;
    const float* w2l = w2 + (size_t)layer * FD * FD;
    for (int k = 0; k < FD; ++k) {
        float wv = w2l[k * FD + lane];
        #pragma unroll
        for (int e = 0; e < 8; ++e) acc[e] += hsh[wid][e][k] * wv;
    }
    #pragma unroll
    for (int e = 0; e < 8; ++e) {
        int ee = e0 + e;
        if (ee < E_) {
            int s = eidx[ee], r = eidx[E_ + ee];
            float A = acc[e] * scal[(size_t)s * FD + lane];
            atomicAdd(&agg0[(size_t)r * FD + lane], A);
        }
    }
}

// Node update: scalars' = agg/16 + (agg/16)^2 + scal*prod_w[spec]; per-node energies to scratch.
// NO contended atomics.
__global__ __launch_bounds__(256) void node_update_k(
    float* __restrict__ scal, float* __restrict__ agg0,
    const int* __restrict__ spec, const float* __restrict__ prod_w,
    const float* __restrict__ readout_w, const float* __restrict__ ro2_w1,
    const float* __restrict__ ro2_b1, const float* __restrict__ ro2_w2,
    const float* __restrict__ charge_w, float* __restrict__ q,
    float* __restrict__ out_nodeE, float* __restrict__ nEl,
    int layer, int last, int N_)
{
    __shared__ float vsh[4][FD];
    int wid = threadIdx.x >> 6, lane = threadIdx.x & 63;
    int n = blockIdx.x * 4 + wid;
    int sp = spec[n];
    size_t idx = (size_t)n * FD + lane;
    float a = agg0[idx] * 0.0625f;
    agg0[idx] = 0.f;                       // pre-zero for next layer
    float v = a + a * a + scal[idx] * prod_w[(layer * NEL + sp) * FD + lane];
    scal[idx] = v;

    float ne;
    if (!last) {
        ne = wred(v * readout_w[layer * FD + lane]);
    } else {
        vsh[wid][lane] = v;
        __syncthreads();
        float h = 0.f;
        if (lane < HML) {
            h = ro2_b1[lane];
            for (int f = 0; f < FD; ++f) h += vsh[wid][f] * ro2_w1[f * HML + lane];
            h = silu(h) * ro2_w2[lane];
        }
        ne = wred(h);
    }
    float qs = wred(v * charge_w[layer * FD + lane]);
    if (lane == 0) {
        nEl[n] = ne;
        out_nodeE[n] += ne;
        q[n] += qs;
    }
}

// Per-graph reductions: one block per graph, zero contention.
// Computes e0 sum, layer-0/1 energy sums, total charge, node part of polarization.
__global__ __launch_bounds__(256) void graph_sum_k(
    const int* __restrict__ spec, const float* __restrict__ ae,
    const float* __restrict__ fc, const float* __restrict__ pos,
    const float* __restrict__ q, const float* __restrict__ nE0,
    const float* __restrict__ nE1, float* __restrict__ acc, int ng)
{
    __shared__ float red[4][8];
    int g = blockIdx.x;
    int tid = threadIdx.x, wid = tid >> 6, lane = tid & 63;
    float se0 = 0.f, s0 = 0.f, s1 = 0.f, sq = 0.f, p0 = 0.f, p1 = 0.f, p2 = 0.f;
    for (int n = g * ng + tid; n < (g + 1) * ng; n += 256) {
        int sp = spec[n];
        float fq = fc[sp];
        se0 += ae[sp];
        s0 += nE0[n];
        s1 += nE1[n];
        sq += q[n];
        p0 += fq * pos[(size_t)n*3+0];
        p1 += fq * pos[(size_t)n*3+1];
        p2 += fq * pos[(size_t)n*3+2];
    }
    float vals[7] = {se0, s0, s1, sq, p0, p1, p2};
    #pragma unroll
    for (int k = 0; k < 7; ++k) {
        float r = wred(vals[k]);
        if (lane == 0) red[wid][k] = r;
    }
    __syncthreads();
    if (tid < 7) {
        float s = red[0][tid] + red[1][tid] + red[2][tid] + red[3][tid];
        if (tid == 0) acc[0 + g] = s;
        else if (tid == 1) acc[20 + g] = s;
        else if (tid == 2) acc[40 + g] = s;
        else if (tid == 3) acc[140 + g] = s;
        else atomicAdd(&acc[80 + g*3 + (tid - 4)], s);   // pol: edge part added by edge_geom
    }
}

// Direct screened Coulomb per graph. Block handles a 64-wide i-chunk of one graph.
__global__ __launch_bounds__(256) void coulomb_k(
    const float* __restrict__ q, const float* __restrict__ pos,
    float* __restrict__ eel, int ng)
{
    __shared__ float qs[1024], px[1024], py[1024], pz[1024];
    __shared__ float wsum[4];
    int g = blockIdx.x >> 4, chunk = blockIdx.x & 15;
    int tid = threadIdx.x;
    const float* qg = q + (size_t)g * ng;
    const float* pg = pos + (size_t)g * ng * 3;
    for (int i = tid; i < ng; i += 256) {
        qs[i] = qg[i];
        px[i] = pg[(size_t)i*3+0]; py[i] = pg[(size_t)i*3+1]; pz[i] = pg[(size_t)i*3+2];
    }
    __syncthreads();
    int i = chunk * 64 + (tid & 63);
    int jq = tid >> 6;                      // wave id: j residue class
    float acc = 0.f;
    if (i < ng) {
        float qi = qs[i], xi = px[i], yi = py[i], zi = pz[i];
        for (int j = jq; j < ng; j += 4) {  // all lanes in a wave share j -> LDS broadcast
            float dx = xi - px[j], dy = yi - py[j], dz = zi - pz[j];
            float r = sqrtf(dx*dx + dy*dy + dz*dz + 1e-12f);
            float kern = (j == i) ? 0.f : erff(0.5f * r) / r;
            acc += qi * qs[j] * kern;
        }
    }
    acc = wred(acc);
    if ((tid & 63) == 0) wsum[tid >> 6] = acc;
    __syncthreads();
    if (tid == 0) atomicAdd(&eel[g], 0.5f * (wsum[0] + wsum[1] + wsum[2] + wsum[3]));
}

__global__ void finalize_k(const float* __restrict__ acc, float* __restrict__ out,
                           int G_, int N_)
{
    int g = threadIdx.x;
    if (g < G_) {
        float a0 = acc[0 + g], a1 = acc[20 + g], a2 = acc[40 + g], ee = acc[60 + g];
        out[g] = a0 + a1 + a2 + ee;                 // total_energy
        float* contrib = out + G_ + N_;             // contributions [G,3]
        contrib[g*3+0] = a0; contrib[g*3+1] = a1; contrib[g*3+2] = a2;
        float* pol = contrib + G_ * 3;              // pol [G,3]
        pol[g*3+0] = acc[80 + g*3+0];
        pol[g*3+1] = acc[80 + g*3+1];
        pol[g*3+2] = acc[80 + g*3+2];
        float* qt = pol + G_ * 3;                   // total_charge [G]
        qt[g] = acc[140 + g];
    }
}

extern "C" void kernel_launch(void* const* d_in, const int* in_sizes, int n_in,
                              void* d_out, int out_size, void* d_ws, size_t ws_size,
                              hipStream_t stream)
{
    const float* node_attrs      = (const float*)d_in[0];
    const float* positions       = (const float*)d_in[1];
    const int*   edge_index      = (const int*)d_in[2];
    const float* atomic_energies = (const float*)d_in[5];
    const float* embed_w         = (const float*)d_in[6];
    const float* radial_w1       = (const float*)d_in[7];
    const float* radial_b1       = (const float*)d_in[8];
    const float* radial_w2       = (const float*)d_in[9];
    const float* prod_w          = (const float*)d_in[10];
    const float* readout_w       = (const float*)d_in[11];
    const float* ro2_w1          = (const float*)d_in[12];
    const float* ro2_b1          = (const float*)d_in[13];
    const float* ro2_w2          = (const float*)d_in[14];
    const float* charge_w        = (const float*)d_in[15];
    const float* flux_w          = (const float*)d_in[16];
    const float* formal_charges  = (const float*)d_in[17];

    int N = in_sizes[0] / NEL;     // 20000
    int E = in_sizes[2] / 2;       // 320000
    const int G_ = GG;             // 20
    int ng = N / G_;               // 1000

    float* ws   = (float*)d_ws;
    float* scal = ws;                              // [N,64]
    float* agg0 = scal + (size_t)N * FD;           // [N,64]
    float* ef   = agg0 + (size_t)N * FD;           // [E,8]
    float* q    = ef + (size_t)E * NBES;           // [N]
    int*   spec = (int*)(q + N);                   // [N]
    float* nE0  = (float*)(spec + N);              // [N]
    float* nE1  = nE0 + N;                         // [N]
    float* acc  = nE1 + N;                         // [160] graph accumulators

    float* out = (float*)d_out;
    float* out_nodeE = out + G_;

    hipMemsetAsync(agg0, 0, (size_t)N * FD * sizeof(float), stream);
    hipMemsetAsync(acc, 0, 160 * sizeof(float), stream);

    setup_nodes_k<<<(N + 255) / 256, 256, 0, stream>>>(
        node_attrs, atomic_energies, formal_charges, spec, q, out_nodeE, N);
    init_scal_k<<<(N * FD + 255) / 256, 256, 0, stream>>>(scal, embed_w, spec, N);
    edge_geom_k<<<128, 256, 0, stream>>>(positions, edge_index, flux_w, ef, acc + 80, E, ng);

    for (int l = 0; l < 2; ++l) {
        edge_mlp_k<<<(E + 31) / 32, 256, 0, stream>>>(
            ef, edge_index, radial_w1, radial_b1, radial_w2, scal, agg0, l, E);
        node_update_k<<<N / 4, 256, 0, stream>>>(
            scal, agg0, spec, prod_w, readout_w, ro2_w1, ro2_b1, ro2_w2,
            charge_w, q, out_nodeE, (l == 0) ? nE0 : nE1,
            l, (l == 1) ? 1 : 0, N);
    }

    graph_sum_k<<<G_, 256, 0, stream>>>(spec, atomic_energies, formal_charges,
                                        positions, q, nE0, nE1, acc, ng);
    coulomb_k<<<G_ * 16, 256, 0, stream>>>(q, positions, acc + 60, ng);
    finalize_k<<<1, 64, 0, stream>>>(acc, out, G_, N);
}

// Round 3
// 330.144 us; speedup vs baseline: 2.4850x; 1.3364x over previous
//
#include <hip/hip_runtime.h>
#include <math.h>

#define NEL 10
#define FD 64
#define NBES 8
#define GG 20
#define HML 16
#define EGB 128   // edge_geom blocks (pol partials sized to this)

typedef __attribute__((ext_vector_type(8))) short short8;
typedef __attribute__((ext_vector_type(4))) float f32x4;

__device__ __forceinline__ float wred(float v) {
    #pragma unroll
    for (int off = 32; off > 0; off >>= 1) v += __shfl_down(v, off, 64);
    return v;
}

__device__ __forceinline__ float silu(float h) {
    return h / (1.f + __expf(-h));
}

__device__ __forceinline__ unsigned short f2bf(float x) {
    unsigned int b = __float_as_uint(x);
    unsigned int r = (b + 0x7FFFu + ((b >> 16) & 1u)) >> 16;
    return (unsigned short)r;
}

// Per-node setup: species, E0, formal charge.
__global__ __launch_bounds__(256) void setup_nodes_k(
    const float* __restrict__ attrs, const float* __restrict__ ae,
    const float* __restrict__ fc, int* __restrict__ spec,
    float* __restrict__ q, float* __restrict__ out_nodeE, int N_)
{
    int n = blockIdx.x * 256 + threadIdx.x;
    if (n < N_) {
        const float* row = attrs + (size_t)n * NEL;
        int sp = 0;
        #pragma unroll
        for (int i = 0; i < NEL; ++i) if (row[i] > 0.5f) sp = i;
        spec[n] = sp;
        out_nodeE[n] = ae[sp];
        q[n] = fc[sp];
    }
}

__global__ __launch_bounds__(256) void init_scal_k(
    float* __restrict__ scal, const float* __restrict__ embed_w,
    const int* __restrict__ spec, int N_)
{
    int idx = blockIdx.x * 256 + threadIdx.x;
    if (idx < N_ * FD) {
        int n = idx >> 6, f = idx & 63;
        scal[idx] = embed_w[spec[n] * FD + f];
    }
}

// Edge geometry: bessel basis via sincos + Chebyshev recurrence; flux; pol partials per block.
__global__ __launch_bounds__(256) void edge_geom_k(
    const float* __restrict__ pos, const int* __restrict__ eidx,
    const float* __restrict__ flux_w, float* __restrict__ ef,
    float* __restrict__ polpart, int E_, int ng)
{
    __shared__ float lpol[GG][3];
    int tid = threadIdx.x;
    if (tid < GG) { lpol[tid][0] = 0.f; lpol[tid][1] = 0.f; lpol[tid][2] = 0.f; }
    __syncthreads();
    float fw[NBES];
    #pragma unroll
    for (int i = 0; i < NBES; ++i) fw[i] = flux_w[i] + flux_w[NBES + i];
    const float PI = 3.14159265358979323846f;
    for (int e = blockIdx.x * 256 + tid; e < E_; e += EGB * 256) {
        int s = eidx[e], r = eidx[E_ + e];
        float dx = pos[(size_t)r*3+0] - pos[(size_t)s*3+0];
        float dy = pos[(size_t)r*3+1] - pos[(size_t)s*3+1];
        float dz = pos[(size_t)r*3+2] - pos[(size_t)s*3+2];
        float len = sqrtf(dx*dx + dy*dy + dz*dz + 1e-12f);
        float x = len * 0.2f;
        float u = 0.f;
        if (x < 1.f) {
            float x2 = x * x;
            float x5 = x2 * x2 * x;
            u = 1.f - 21.f * x5 + 35.f * x5 * x - 15.f * x5 * x2;
        }
        float pref = 0.6324555320336759f / len * u;   // sqrt(2/5)/r * u
        float theta = PI * x;
        float s1, c1;
        __sincosf(theta, &s1, &c1);
        float c2 = 2.f * c1;
        float sp_ = 0.f, sn = s1;                      // sin(0), sin(theta)
        float flux = 0.f;
        float* efe = ef + (size_t)e * NBES;
        #pragma unroll
        for (int i = 0; i < NBES; ++i) {
            float rb = pref * sn;
            efe[i] = rb;
            flux += rb * fw[i];
            float nx = c2 * sn - sp_;                  // sin((n+1)theta)
            sp_ = sn; sn = nx;
        }
        int g = r / ng;
        atomicAdd(&lpol[g][0], flux * dx);
        atomicAdd(&lpol[g][1], flux * dy);
        atomicAdd(&lpol[g][2], flux * dz);
    }
    __syncthreads();
    if (tid < GG * 3) polpart[blockIdx.x * (GG * 3) + tid] = lpol[tid / 3][tid % 3];
}

// Radial MLP + message + scatter, MFMA version. Block = 64 edges.
// Phase 1 (scalar): h[64e][64k] = silu(ef@W1+b1) -> LDS bf16.
// Phase 2 (MFMA): A[64e][64f] = h @ W2 via mfma_f32_16x16x32_bf16, 4 waves x 8 MFMA.
// Epilogue: A *= scal[snd], atomicAdd into agg0[rcv].
__global__ __launch_bounds__(256) void edge_mlp_k(
    const float* __restrict__ ef, const int* __restrict__ eidx,
    const float* __restrict__ w1, const float* __restrict__ b1,
    const float* __restrict__ w2, const float* __restrict__ scal,
    float* __restrict__ agg0, int layer, int E_)
{
    __shared__ __align__(16) unsigned short hsh[64 * 72];
    __shared__ __align__(16) unsigned short w2t[64 * 72];
    __shared__ float w1b[8 * 64 + 64];
    __shared__ int sndl[64], rcvl[64];

    int t = threadIdx.x;
    int ebase = blockIdx.x * 64;

    // stage edge indices, W1+b1, W2^T (bf16)
    if (t < 64) {
        sndl[t] = eidx[ebase + t];
        rcvl[t] = eidx[E_ + ebase + t];
        w1b[512 + t] = b1[layer * FD + t];
    }
    for (int i = t; i < 512; i += 256) w1b[i] = w1[layer * 512 + i];
    #pragma unroll
    for (int i = 0; i < 16; ++i) {
        int linear = i * 256 + t;              // = k*64 + f
        int k = linear >> 6, f = linear & 63;
        w2t[f * 72 + k] = f2bf(w2[layer * 4096 + linear]);
    }
    __syncthreads();

    // phase 1: thread -> edge e = t&63, k-range kb..kb+15
    {
        int e = t & 63, kb = (t >> 6) * 16;
        const f32x4* e4 = (const f32x4*)(ef + (size_t)(ebase + e) * NBES);
        f32x4 A0 = e4[0], A1 = e4[1];
        float efr[8] = {A0.x, A0.y, A0.z, A0.w, A1.x, A1.y, A1.z, A1.w};
        unsigned int hv[8];
        #pragma unroll
        for (int jp = 0; jp < 8; ++jp) {
            unsigned int pk = 0;
            #pragma unroll
            for (int half = 0; half < 2; ++half) {
                int k = kb + jp * 2 + half;
                float h = w1b[512 + k];
                #pragma unroll
                for (int i = 0; i < 8; ++i) h += efr[i] * w1b[i * 64 + k];
                pk |= ((unsigned int)f2bf(silu(h))) << (16 * half);
            }
            hv[jp] = pk;
        }
        uint4* dst = (uint4*)&hsh[e * 72 + kb];
        dst[0] = make_uint4(hv[0], hv[1], hv[2], hv[3]);
        dst[1] = make_uint4(hv[4], hv[5], hv[6], hv[7]);
    }
    __syncthreads();

    // phase 2: wave w handles edge rows 16w..16w+15, all 4 feature tiles
    int w = t >> 6, lane = t & 63;
    int mrow = lane & 15, quad = lane >> 4;
    const short8* ap = (const short8*)&hsh[(16 * w + mrow) * 72 + quad * 8];
    short8 a0 = ap[0];
    short8 a1 = *(const short8*)&hsh[(16 * w + mrow) * 72 + 32 + quad * 8];
    f32x4 c[4];
    #pragma unroll
    for (int nt = 0; nt < 4; ++nt) {
        short8 b0 = *(const short8*)&w2t[(nt * 16 + mrow) * 72 + quad * 8];
        short8 bv = *(const short8*)&w2t[(nt * 16 + mrow) * 72 + 32 + quad * 8];
        f32x4 cc = {0.f, 0.f, 0.f, 0.f};
        cc = __builtin_amdgcn_mfma_f32_16x16x32_bf16(a0, b0, cc, 0, 0, 0);
        cc = __builtin_amdgcn_mfma_f32_16x16x32_bf16(a1, bv, cc, 0, 0, 0);
        c[nt] = cc;
    }
    // epilogue: C row (edge) = 16w + quad*4 + reg, col (feature) = nt*16 + mrow
    #pragma unroll
    for (int reg = 0; reg < 4; ++reg) {
        int ee = 16 * w + quad * 4 + reg;
        int s = sndl[ee], rv = rcvl[ee];
        const float* srow = scal + (size_t)s * FD;
        float* arow = agg0 + (size_t)rv * FD;
        #pragma unroll
        for (int nt = 0; nt < 4; ++nt) {
            int f = nt * 16 + mrow;
            atomicAdd(&arow[f], c[nt][reg] * srow[f]);
        }
    }
}

// Node update: scalars' = agg/16 + (agg/16)^2 + scal*prod_w[spec]; per-node energies to scratch.
__global__ __launch_bounds__(256) void node_update_k(
    float* __restrict__ scal, float* __restrict__ agg0,
    const int* __restrict__ spec, const float* __restrict__ prod_w,
    const float* __restrict__ readout_w, const float* __restrict__ ro2_w1,
    const float* __restrict__ ro2_b1, const float* __restrict__ ro2_w2,
    const float* __restrict__ charge_w, float* __restrict__ q,
    float* __restrict__ out_nodeE, float* __restrict__ nEl,
    int layer, int last, int N_)
{
    __shared__ float vsh[4][FD];
    int wid = threadIdx.x >> 6, lane = threadIdx.x & 63;
    int n = blockIdx.x * 4 + wid;
    int sp = spec[n];
    size_t idx = (size_t)n * FD + lane;
    float a = agg0[idx] * 0.0625f;
    agg0[idx] = 0.f;                       // pre-zero for next layer
    float v = a + a * a + scal[idx] * prod_w[(layer * NEL + sp) * FD + lane];
    scal[idx] = v;

    float ne;
    if (!last) {
        ne = wred(v * readout_w[layer * FD + lane]);
    } else {
        vsh[wid][lane] = v;
        __syncthreads();
        float h = 0.f;
        if (lane < HML) {
            h = ro2_b1[lane];
            for (int f = 0; f < FD; ++f) h += vsh[wid][f] * ro2_w1[f * HML + lane];
            h = silu(h) * ro2_w2[lane];
        }
        ne = wred(h);
    }
    float qs = wred(v * charge_w[layer * FD + lane]);
    if (lane == 0) {
        nEl[n] = ne;
        out_nodeE[n] += ne;
        q[n] += qs;
    }
}

// Per-graph reductions: one block per graph, zero contention.
__global__ __launch_bounds__(256) void graph_sum_k(
    const int* __restrict__ spec, const float* __restrict__ ae,
    const float* __restrict__ fc, const float* __restrict__ pos,
    const float* __restrict__ q, const float* __restrict__ nE0,
    const float* __restrict__ nE1, const float* __restrict__ polpart,
    float* __restrict__ acc, int ng)
{
    __shared__ float red[4][8];
    int g = blockIdx.x;
    int tid = threadIdx.x, wid = tid >> 6, lane = tid & 63;
    float se0 = 0.f, s0 = 0.f, s1 = 0.f, sq = 0.f, p0 = 0.f, p1 = 0.f, p2 = 0.f;
    for (int n = g * ng + tid; n < (g + 1) * ng; n += 256) {
        int sp = spec[n];
        float fq = fc[sp];
        se0 += ae[sp];
        s0 += nE0[n];
        s1 += nE1[n];
        sq += q[n];
        p0 += fq * pos[(size_t)n*3+0];
        p1 += fq * pos[(size_t)n*3+1];
        p2 += fq * pos[(size_t)n*3+2];
    }
    float vals[7] = {se0, s0, s1, sq, p0, p1, p2};
    #pragma unroll
    for (int k = 0; k < 7; ++k) {
        float r = wred(vals[k]);
        if (lane == 0) red[wid][k] = r;
    }
    __syncthreads();
    if (tid < 7) {
        float s = red[0][tid] + red[1][tid] + red[2][tid] + red[3][tid];
        if (tid == 0) acc[0 + g] = s;
        else if (tid == 1) acc[20 + g] = s;
        else if (tid == 2) acc[40 + g] = s;
        else if (tid == 3) acc[140 + g] = s;
        else {
            int cdim = tid - 4;
            for (int b = 0; b < EGB; ++b) s += polpart[b * (GG * 3) + g * 3 + cdim];
            acc[80 + g * 3 + cdim] = s;
        }
    }
}

// Direct screened Coulomb. Block = (graph, 64-wide i-chunk, j-half).
__global__ __launch_bounds__(256) void coulomb_k(
    const float* __restrict__ q, const float* __restrict__ pos,
    float* __restrict__ eel, int ng)
{
    __shared__ float qs[1024], px[1024], py[1024], pz[1024];
    __shared__ float wsum[4];
    int g = blockIdx.x >> 5, chunk = (blockIdx.x >> 1) & 15, jh = blockIdx.x & 1;
    int tid = threadIdx.x;
    const float* qg = q + (size_t)g * ng;
    const float* pg = pos + (size_t)g * ng * 3;
    for (int i = tid; i < ng; i += 256) {
        qs[i] = qg[i];
        px[i] = pg[(size_t)i*3+0]; py[i] = pg[(size_t)i*3+1]; pz[i] = pg[(size_t)i*3+2];
    }
    __syncthreads();
    int i = chunk * 64 + (tid & 63);
    int j0 = jh * 4 + (tid >> 6);
    float acc = 0.f;
    if (i < ng) {
        float qi = qs[i], xi = px[i], yi = py[i], zi = pz[i];
        for (int j = j0; j < ng; j += 8) {
            float dx = xi - px[j], dy = yi - py[j], dz = zi - pz[j];
            float d2 = dx*dx + dy*dy + dz*dz + 1e-12f;
            float rinv = __frsqrt_rn(d2);
            float r = d2 * rinv;
            float x = 0.5f * r;
            float tt = __frcp_rn(1.f + 0.3275911f * x);
            float poly = ((((1.061405429f*tt - 1.453152027f)*tt + 1.421413741f)*tt
                           - 0.284496736f)*tt + 0.254829592f)*tt;
            float erfv = 1.f - poly * __expf(-x * x);
            float kern = (j == i) ? 0.f : erfv * rinv;
            acc += qi * qs[j] * kern;
        }
    }
    acc = wred(acc);
    if ((tid & 63) == 0) wsum[tid >> 6] = acc;
    __syncthreads();
    if (tid == 0) atomicAdd(&eel[g], 0.5f * (wsum[0] + wsum[1] + wsum[2] + wsum[3]));
}

__global__ void finalize_k(const float* __restrict__ acc, float* __restrict__ out,
                           int G_, int N_)
{
    int g = threadIdx.x;
    if (g < G_) {
        float a0 = acc[0 + g], a1 = acc[20 + g], a2 = acc[40 + g], ee = acc[60 + g];
        out[g] = a0 + a1 + a2 + ee;                 // total_energy
        float* contrib = out + G_ + N_;             // contributions [G,3]
        contrib[g*3+0] = a0; contrib[g*3+1] = a1; contrib[g*3+2] = a2;
        float* pol = contrib + G_ * 3;              // pol [G,3]
        pol[g*3+0] = acc[80 + g*3+0];
        pol[g*3+1] = acc[80 + g*3+1];
        pol[g*3+2] = acc[80 + g*3+2];
        float* qt = pol + G_ * 3;                   // total_charge [G]
        qt[g] = acc[140 + g];
    }
}

extern "C" void kernel_launch(void* const* d_in, const int* in_sizes, int n_in,
                              void* d_out, int out_size, void* d_ws, size_t ws_size,
                              hipStream_t stream)
{
    const float* node_attrs      = (const float*)d_in[0];
    const float* positions       = (const float*)d_in[1];
    const int*   edge_index      = (const int*)d_in[2];
    const float* atomic_energies = (const float*)d_in[5];
    const float* embed_w         = (const float*)d_in[6];
    const float* radial_w1       = (const float*)d_in[7];
    const float* radial_b1       = (const float*)d_in[8];
    const float* radial_w2       = (const float*)d_in[9];
    const float* prod_w          = (const float*)d_in[10];
    const float* readout_w       = (const float*)d_in[11];
    const float* ro2_w1          = (const float*)d_in[12];
    const float* ro2_b1          = (const float*)d_in[13];
    const float* ro2_w2          = (const float*)d_in[14];
    const float* charge_w        = (const float*)d_in[15];
    const float* flux_w          = (const float*)d_in[16];
    const float* formal_charges  = (const float*)d_in[17];

    int N = in_sizes[0] / NEL;     // 20000
    int E = in_sizes[2] / 2;       // 320000
    const int G_ = GG;             // 20
    int ng = N / G_;               // 1000

    float* ws      = (float*)d_ws;
    float* scal    = ws;                               // [N,64]
    float* agg0    = scal + (size_t)N * FD;            // [N,64]
    float* ef      = agg0 + (size_t)N * FD;            // [E,8]
    float* q       = ef + (size_t)E * NBES;            // [N]
    int*   spec    = (int*)(q + N);                    // [N]
    float* nE0     = (float*)(spec + N);               // [N]
    float* nE1     = nE0 + N;                          // [N]
    float* polpart = nE1 + N;                          // [EGB*60]
    float* acc     = polpart + EGB * (GG * 3);         // [160]

    float* out = (float*)d_out;
    float* out_nodeE = out + G_;

    hipMemsetAsync(agg0, 0, (size_t)N * FD * sizeof(float), stream);
    hipMemsetAsync(acc, 0, 160 * sizeof(float), stream);

    setup_nodes_k<<<(N + 255) / 256, 256, 0, stream>>>(
        node_attrs, atomic_energies, formal_charges, spec, q, out_nodeE, N);
    init_scal_k<<<(N * FD + 255) / 256, 256, 0, stream>>>(scal, embed_w, spec, N);
    edge_geom_k<<<EGB, 256, 0, stream>>>(positions, edge_index, flux_w, ef, polpart, E, ng);

    for (int l = 0; l < 2; ++l) {
        edge_mlp_k<<<E / 64, 256, 0, stream>>>(
            ef, edge_index, radial_w1, radial_b1, radial_w2, scal, agg0, l, E);
        node_update_k<<<N / 4, 256, 0, stream>>>(
            scal, agg0, spec, prod_w, readout_w, ro2_w1, ro2_b1, ro2_w2,
            charge_w, q, out_nodeE, (l == 0) ? nE0 : nE1,
            l, (l == 1) ? 1 : 0, N);
    }

    graph_sum_k<<<G_, 256, 0, stream>>>(spec, atomic_energies, formal_charges,
                                        positions, q, nE0, nE1, polpart, acc, ng);
    coulomb_k<<<G_ * 32, 256, 0, stream>>>(q, positions, acc + 60, ng);
    finalize_k<<<1, 64, 0, stream>>>(acc, out, G_, N);
}